// Round 10
// baseline (339.494 us; speedup 1.0000x reference)
//
#include <hip/hip_runtime.h>
#include <math.h>

#define BB 2
#define SS 2048
#define DD 2048
#define QH 16
#define NKV 4
#define HD 128
#define REP 4           // QH / NKV
#define NEG_INF_F (-1e9f)

typedef __bf16 bfrag __attribute__((ext_vector_type(8)));   // 4 VGPRs
typedef float  ffrag __attribute__((ext_vector_type(4)));   // 4 VGPRs

__device__ inline unsigned short f2bf(float f) {
    unsigned u = __builtin_bit_cast(unsigned, f);
    u += 0x7fff + ((u >> 16) & 1);          // round-to-nearest-even
    return (unsigned short)(u >> 16);
}
__device__ inline float bf2f(unsigned short u) {
    unsigned v = (unsigned)u << 16;
    return __builtin_bit_cast(float, v);
}
__device__ inline bfrag ld_frag(const unsigned short* p) {
    uint4 u = *(const uint4*)p;
    return __builtin_bit_cast(bfrag, u);
}
__device__ inline void async16(const void* g, void* l) {
    __builtin_amdgcn_global_load_lds(
        (const __attribute__((address_space(1))) unsigned int*)g,
        (__attribute__((address_space(3))) unsigned int*)l, 16, 0, 0);
}
// pack two floats to packed bf16
__device__ inline unsigned pkbf(float a, float b) {
    unsigned short ua = __builtin_bit_cast(unsigned short, (__bf16)a);
    unsigned short ub = __builtin_bit_cast(unsigned short, (__bf16)b);
    return (unsigned)ua | ((unsigned)ub << 16);
}

// ---------------------------------------------------------------------------
// Kernel P: fused prep — cast_x + all weight transpose-casts in ONE launch.
//   blocks [0,4096):        cast x fp32->bf16, 2048 elems/block
//   blocks [4096,10240):    tcast Wq/Wk/Wv (R=2048,C=128, 24 batches)
//   blocks [10240,14336):   tcast Wo (R=C=2048)
// ---------------------------------------------------------------------------
__global__ __launch_bounds__(256) void prep_kernel(
    const float* __restrict__ x, unsigned short* __restrict__ xb,
    const float* __restrict__ Wq, const float* __restrict__ Wk,
    const float* __restrict__ Wv, const float* __restrict__ Wo,
    unsigned short* __restrict__ Wqkvt, unsigned short* __restrict__ Wot)
{
    __shared__ float tile[32][33];
    const int blk = blockIdx.x;
    const int tid = threadIdx.x;

    if (blk < 4096) {
        const int i = blk * 2048 + tid * 8;
        float4 a = *(const float4*)(x + i);
        float4 b = *(const float4*)(x + i + 4);
        unsigned short o[8];
        o[0] = f2bf(a.x); o[1] = f2bf(a.y); o[2] = f2bf(a.z); o[3] = f2bf(a.w);
        o[4] = f2bf(b.x); o[5] = f2bf(b.y); o[6] = f2bf(b.z); o[7] = f2bf(b.w);
        *(uint4*)(xb + i) = *(uint4*)o;
        return;
    }

    const float* in;
    unsigned short* out;
    int R, C, bx, by;
    if (blk < 10240) {
        const int lw = blk - 4096;
        const int z  = lw >> 8;            // 0..23
        const int r  = lw & 255;
        bx = r & 3; by = r >> 2;
        R = 2048; C = 128;
        if (z < 16)      { in = Wq + (size_t)z * 2048 * 128;
                           out = Wqkvt + (size_t)z * 128 * 2048; }
        else if (z < 20) { in = Wk + (size_t)(z - 16) * 2048 * 128;
                           out = Wqkvt + (size_t)(16 + (z - 16)) * 128 * 2048; }
        else             { in = Wv + (size_t)(z - 20) * 2048 * 128;
                           out = Wqkvt + (size_t)(20 + (z - 20)) * 128 * 2048; }
    } else {
        const int lw = blk - 10240;
        bx = lw & 63; by = lw >> 6;
        R = 2048; C = 2048;
        in = Wo; out = Wot;
    }
    const int c0 = bx * 32, r0 = by * 32;
    const int tx = tid & 31, ty = tid >> 5;   // ty: 0..7
    #pragma unroll
    for (int k = 0; k < 4; ++k)
        tile[ty + 8 * k][tx] = in[(size_t)(r0 + ty + 8 * k) * C + c0 + tx];
    __syncthreads();
    #pragma unroll
    for (int k = 0; k < 4; ++k)
        out[(size_t)(c0 + ty + 8 * k) * R + r0 + tx] =
            f2bf(tile[tx][ty + 8 * k]);
}

// ---------------------------------------------------------------------------
// Kernel C: bf16 MFMA GEMM v6 (round-9, measured 84.4 µs qkv) — BK=64 +
// double-buffer, XOR-8 LDS swizzle (0 bank conflicts), natural block order
// (both XCD remaps measured worse).
// mode 0: fp32 out [row][2048] (oproj).
// mode 1: qkv — q,k natural bf16; v stored TRANSPOSED to vt[b][n][h][s].
// ---------------------------------------------------------------------------
__global__ __launch_bounds__(256) void gemm_bt_kernel(
    const unsigned short* __restrict__ A,
    const unsigned short* __restrict__ Bt,
    unsigned short* __restrict__ q_out, unsigned short* __restrict__ k_out,
    unsigned short* __restrict__ vt_out, float* __restrict__ f_out,
    int mode)
{
    const int m0 = blockIdx.x * 128;
    const int n0 = blockIdx.y * 128;
    const int tid  = threadIdx.x;
    const int w    = tid >> 6, lane = tid & 63;
    const int l16  = lane & 15, quad = lane >> 4;
    const int wm = (w >> 1) * 64, wn = (w & 1) * 64;
    const int sw8 = l16 & 7;                  // read-side swizzle key

    __shared__ unsigned short As[2][128 * 64];   // 32 KB  [buf][m][k64]
    __shared__ unsigned short Bs[2][128 * 64];   // 32 KB  [buf][n][k64]

    ffrag acc[4][4];
    #pragma unroll
    for (int mi = 0; mi < 4; ++mi)
        #pragma unroll
        for (int ni = 0; ni < 4; ++ni)
            acc[mi][ni] = (ffrag){0.f, 0.f, 0.f, 0.f};

    auto stage = [&](int d, int k0) {
        #pragma unroll
        for (int j = 0; j < 4; ++j) {
            const int i   = j * 256 + tid;        // granule 0..1023
            const int row = i >> 3;
            const int sl  = (i & 7) ^ (row & 7);
            async16(&A [(size_t)(m0 + row) * 2048 + k0 + sl * 8],
                    (char*)&As[d][0] + i * 16);
            async16(&Bt[(size_t)(n0 + row) * 2048 + k0 + sl * 8],
                    (char*)&Bs[d][0] + i * 16);
        }
    };

    stage(0, 0);
    __syncthreads();              // prologue drain: buffer 0 ready
    int cur = 0;
    for (int k0 = 0; k0 < 2048; k0 += 64) {
        if (k0 + 64 < 2048) stage(cur ^ 1, k0 + 64);

        #pragma unroll
        for (int c2 = 0; c2 < 2; ++c2) {
            bfrag af[4], bfr[4];
            #pragma unroll
            for (int mi = 0; mi < 4; ++mi)
                af[mi] = ld_frag(&As[cur][(wm + mi * 16 + l16) * 64
                                          + (((c2 * 4 + quad) ^ sw8) * 8)]);
            #pragma unroll
            for (int ni = 0; ni < 4; ++ni)
                bfr[ni] = ld_frag(&Bs[cur][(wn + ni * 16 + l16) * 64
                                           + (((c2 * 4 + quad) ^ sw8) * 8)]);
            #pragma unroll
            for (int mi = 0; mi < 4; ++mi)
                #pragma unroll
                for (int ni = 0; ni < 4; ++ni)
                    acc[mi][ni] = __builtin_amdgcn_mfma_f32_16x16x32_bf16(
                        af[mi], bfr[ni], acc[mi][ni], 0, 0, 0);
        }

        __syncthreads();
        cur ^= 1;
    }

    if (mode == 0) {
        #pragma unroll
        for (int mi = 0; mi < 4; ++mi)
            #pragma unroll
            for (int ni = 0; ni < 4; ++ni) {
                const int col = n0 + wn + ni * 16 + l16;
                #pragma unroll
                for (int r = 0; r < 4; ++r) {
                    const int row = m0 + wm + mi * 16 + quad * 4 + r;
                    f_out[(size_t)row * 2048 + col] = acc[mi][ni][r];
                }
            }
    } else if (n0 < 2560) {
        unsigned short* dst;
        int colbase, stride;
        if (n0 < 2048)      { dst = q_out; colbase = n0;        stride = 2048; }
        else                { dst = k_out; colbase = n0 - 2048; stride = 512;  }
        #pragma unroll
        for (int mi = 0; mi < 4; ++mi)
            #pragma unroll
            for (int ni = 0; ni < 4; ++ni) {
                const int col = colbase + wn + ni * 16 + l16;
                #pragma unroll
                for (int r = 0; r < 4; ++r) {
                    const int row = m0 + wm + mi * 16 + quad * 4 + r;
                    dst[(size_t)row * stride + col] = f2bf(acc[mi][ni][r]);
                }
            }
    } else {
        const int c3 = n0 - 2560;
        #pragma unroll
        for (int mi = 0; mi < 4; ++mi)
            #pragma unroll
            for (int ni = 0; ni < 4; ++ni) {
                const int col = c3 + wn + ni * 16 + l16;   // 0..511
                const int nh = col >> 7, h = col & 127;
                const int row0 = m0 + wm + mi * 16 + quad * 4;
                const int b = row0 >> 11, s = row0 & 2047;
                unsigned short pk[4];
                #pragma unroll
                for (int r = 0; r < 4; ++r) pk[r] = f2bf(acc[mi][ni][r]);
                *(uint2*)&vt_out[(((size_t)b * NKV + nh) * HD + h) * SS + s] =
                    *(uint2*)pk;
            }
    }
}

// ---------------------------------------------------------------------------
// Kernel D: RoPE in-place on bf16 q and k. Softmax scale folded into q.
// ---------------------------------------------------------------------------
__global__ void rope_kernel(unsigned short* __restrict__ q,
                            unsigned short* __restrict__ k,
                            const int* __restrict__ positions)
{
    const int qpairs = BB * SS * QH * 64;
    const int kpairs = BB * SS * NKV * 64;
    int idx = blockIdx.x * blockDim.x + threadIdx.x;
    unsigned short* base;
    int nh;
    if (idx < qpairs) { base = q; nh = QH; }
    else {
        idx -= qpairs;
        if (idx >= kpairs) return;
        base = k; nh = NKV;
    }
    const int hh   = idx & 63;
    const int rest = idx >> 6;
    const int head = rest % nh;
    const int bs   = rest / nh;
    const int s    = bs % SS;

    unsigned short* p = base + ((size_t)bs * nh + head) * HD;
    const float pos = (float)positions[s];
    const float inv_ts = powf(10000.0f, -(float)hh * (1.0f / 64.0f));
    const float angle = pos * inv_ts;
    const float sn = sinf(angle), cs = cosf(angle);
    const float sc_ = (nh == QH) ? 0.08838834764831845f : 1.0f; // 1/sqrt(128)
    const float x1 = bf2f(p[hh]), x2 = bf2f(p[hh + 64]);
    p[hh]      = f2bf((x1 * cs - x2 * sn) * sc_);
    p[hh + 64] = f2bf((x2 * cs + x1 * sn) * sc_);
}

// ---------------------------------------------------------------------------
// Kernel E: causal flash attention v10 — 3 blocks/CU via LDS diet.
//  v8 base (verified): swapped QK^T + lane-local softmax, defer-max, XOR-8
//  K/V swizzle, setprio, XCD chunking, paired tiles.
//  v10 changes:
//  - K staged in 32-row tiles, double-buffered: Ks[2][2][32][64] = 16 KB
//    (was 32). Same 128-B-row XOR-8 read pattern, 66 rounds of k-step 32.
//  - V stays 64-wide (dbuf 32 KB): its proven conflict-free read pattern is
//    kept BIT-IDENTICAL; V buffer flips every 2 rounds (two vmcnt(0)
//    barriers between overwrite and first read; race-audited). 64-B V rows
//    would be un-swizzlable (row index contributes only 1 bank bit).
//  - Ps compacted to [4][16][36] = 4.6 KB (single P fragment per round).
//  - Total LDS 53,760 B -> 3 blocks/CU = 12 waves (was 2/8): +50% latency
//    hiding on the QK^T->softmax->PV serial chain.
//  - Full-mask guard: at toff=32 waves 0,1 have no unmasked columns; they
//    must SKIP the round entirely (else exp(S - m) with all-masked input
//    corrupts m -> p=1). Wave-uniform branch; barrier still hit by all.
// ---------------------------------------------------------------------------
__global__ __launch_bounds__(256, 3) void attn_kernel(
    const unsigned short* __restrict__ qb,
    const unsigned short* __restrict__ kb,
    const unsigned short* __restrict__ vt,
    unsigned short* __restrict__ o)
{
    // XCD-aware remap: flat = bh*16 + tile_x, chunks of 64 per XCD
    int f = blockIdx.y * 16 + blockIdx.x;
    f = (f & 7) * 64 + (f >> 3);                   // 512 blocks, bijective
    const int bh = f >> 4;
    const int bx = f & 15;

    const int b  = bh / QH, qh = bh % QH;
    const int n  = qh / REP;

    const int tid  = threadIdx.x;
    const int w    = tid >> 6;
    const int lane = tid & 63;
    const int l16  = lane & 15;
    const int quad = lane >> 4;
    const int sw   = l16 & 7;                      // read-side swizzle key

    __shared__ unsigned short Ks[2][2][32][64];    // 16 KB [buf][cc][t32][h64]
    __shared__ unsigned short Vs[2][128][64];      // 32 KB [buf][h][t64]
    __shared__ unsigned short Ps[4][16][36];       // 4.5 KB [wave][q][k32+pad]

    const unsigned short* kbase = kb + (size_t)b * (SS * NKV * HD) + n * HD;
    const unsigned short* vbase = vt + ((size_t)b * NKV + n) * HD * SS;

    for (int ph = 0; ph < 2; ++ph) {
        const int tile = ph == 0 ? (31 - bx) : bx;
        const int s0 = tile * 64;
        const int rbase = s0 + w * 16 + quad * 4;   // oacc row base
        const int thr   = w * 16 + l16;             // this lane's q (in-tile)

        bfrag qf[4];
        {
            const unsigned short* qp =
                qb + ((size_t)(b * SS + s0 + w * 16 + l16) * QH + qh) * HD
                   + quad * 8;
            #pragma unroll
            for (int c = 0; c < 4; ++c) qf[c] = ld_frag(qp + c * 32);
        }
        ffrag oacc[8];
        #pragma unroll
        for (int t = 0; t < 8; ++t) oacc[t] = (ffrag){0.f, 0.f, 0.f, 0.f};
        float mr = -1e30f, lr = 0.0f;               // state for q-row l16

        // prologue: K tile [0,32) -> Kbuf0 (2/thread), V tile [0,64) -> Vbuf0
        #pragma unroll
        for (int j = 0; j < 2; ++j) {
            const int i = j * 256 + tid;            // K granule 0..511
            const int cc = i >> 8, t = (i >> 3) & 31, sl = i & 7;
            async16(kbase + (size_t)t * (NKV * HD) + cc * 64
                          + ((sl ^ (t & 7)) * 8),
                    (char*)&Ks[0][0][0][0] + i * 16);
        }
        #pragma unroll
        for (int j = 0; j < 4; ++j) {
            const int i = j * 256 + tid;            // V granule 0..1023
            const int h = i >> 3, sl = i & 7;
            async16(vbase + (size_t)h * SS + ((sl ^ (h & 7)) * 8),
                    (char*)&Vs[0][0][0] + i * 16);
        }
        __syncthreads();

        for (int t0 = 0; t0 <= s0 + 32; t0 += 32) {
            const int pk = (t0 >> 5) & 1;
            const int pv = (t0 >> 6) & 1;

            // stage next K tile [t0+32, t0+64) into Kbuf pk^1
            if (t0 <= s0) {
                #pragma unroll
                for (int j = 0; j < 2; ++j) {
                    const int i = j * 256 + tid;
                    const int cc = i >> 8, t = (i >> 3) & 31, sl = i & 7;
                    async16(kbase + (size_t)(t0 + 32 + t) * (NKV * HD)
                                  + cc * 64 + ((sl ^ (t & 7)) * 8),
                            (char*)&Ks[pk ^ 1][0][0][0] + i * 16);
                }
            }
            // stage next V tile [t0+64, t0+128) into Vbuf pv^1 (every other
            // round; lands >= 2 barriers before first read)
            if ((t0 & 32) == 0 && t0 + 64 <= s0 + 32) {
                #pragma unroll
                for (int j = 0; j < 4; ++j) {
                    const int i = j * 256 + tid;
                    const int h = i >> 3, sl = i & 7;
                    async16(vbase + (size_t)h * SS + t0 + 64
                                  + ((sl ^ (h & 7)) * 8),
                            (char*)&Vs[pv ^ 1][0][0] + i * 16);
                }
            }

            const int toff = t0 - s0;
            if (toff <= w * 16 + 15) {   // wave-uniform: skip fully-masked
                // --- QK^T (swapped): C[k-sub][q], k = t0 + ts*16 + 4*quad+r
                ffrag sc[2];
                sc[0] = (ffrag){0.f, 0.f, 0.f, 0.f};
                sc[1] = (ffrag){0.f, 0.f, 0.f, 0.f};
                __builtin_amdgcn_s_setprio(1);
                #pragma unroll
                for (int c = 0; c < 4; ++c) {
                    const int cc = c >> 1, cb = (c & 1) * 4;
                    #pragma unroll
                    for (int ts = 0; ts < 2; ++ts) {
                        bfrag kfr = ld_frag(
                            &Ks[pk][cc][ts * 16 + l16][((cb + quad) ^ sw) * 8]);
                        sc[ts] = __builtin_amdgcn_mfma_f32_16x16x32_bf16(
                            kfr, qf[c], sc[ts], 0, 0, 0);
                    }
                }
                __builtin_amdgcn_s_setprio(0);

                // --- causal mask (only the 2 diagonal rounds)
                if (toff >= 0) {
                    #pragma unroll
                    for (int ts = 0; ts < 2; ++ts) {
                        const int col0 = toff + ts * 16 + quad * 4;
                        #pragma unroll
                        for (int r = 0; r < 4; ++r)
                            if (col0 + r > thr) sc[ts][r] = NEG_INF_F;
                    }
                }

                // --- lane-local online softmax (q-row l16)
                float tmax;
                {
                    float a0 = fmaxf(fmaxf(sc[0][0], sc[0][1]),
                                     fmaxf(sc[0][2], sc[0][3]));
                    float a1 = fmaxf(fmaxf(sc[1][0], sc[1][1]),
                                     fmaxf(sc[1][2], sc[1][3]));
                    tmax = fmaxf(a0, a1);
                }
                tmax = fmaxf(tmax, __shfl_xor(tmax, 16));
                tmax = fmaxf(tmax, __shfl_xor(tmax, 32));

                if (__any(tmax > mr + 8.0f)) {
                    const float mnew  = fmaxf(mr, tmax);
                    const float alpha = __expf(mr - mnew);
                    lr *= alpha;
                    mr = mnew;
                    #pragma unroll
                    for (int r = 0; r < 4; ++r) {
                        const float ar =
                            __shfl(alpha, (lane & 48) | (quad * 4 + r));
                        #pragma unroll
                        for (int t = 0; t < 8; ++t) oacc[t][r] *= ar;
                    }
                }

                float ps = 0.f;
                #pragma unroll
                for (int ts = 0; ts < 2; ++ts) {
                    const float p0 = __expf(sc[ts][0] - mr);
                    const float p1 = __expf(sc[ts][1] - mr);
                    const float p2 = __expf(sc[ts][2] - mr);
                    const float p3 = __expf(sc[ts][3] - mr);
                    ps += (p0 + p1) + (p2 + p3);
                    uint2 pk2;
                    pk2.x = pkbf(p0, p1);
                    pk2.y = pkbf(p2, p3);
                    *(uint2*)&Ps[w][l16][ts * 16 + quad * 4] = pk2;
                }
                ps += __shfl_xor(ps, 16);
                ps += __shfl_xor(ps, 32);
                lr += ps;
                // wave-private Ps: same-wave LDS ordering, no barrier needed

                // --- PV on V buffer pv, 32-wide k-slice at offset t0&32
                const int sb = (t0 & 32) >> 3;      // 16B slot base (0 or 4)
                __builtin_amdgcn_s_setprio(1);
                bfrag pf = ld_frag(&Ps[w][l16][quad * 8]);
                #pragma unroll
                for (int t = 0; t < 8; ++t) {
                    bfrag vf = ld_frag(
                        &Vs[pv][t * 16 + l16][((sb + quad) ^ sw) * 8]);
                    oacc[t] = __builtin_amdgcn_mfma_f32_16x16x32_bf16(
                        pf, vf, oacc[t], 0, 0, 0);
                }
                __builtin_amdgcn_s_setprio(0);
            }

            // one barrier per round: drains staging (vmcnt0) after compute,
            // orders this round's LDS reads vs upcoming overwrites
            __syncthreads();
        }

        // --- epilogue (oacc rows are q = rbase + r; l at lane 4*quad+r)
        #pragma unroll
        for (int r = 0; r < 4; ++r) {
            const float lrr  = __shfl(lr, (lane & 48) | (quad * 4 + r));
            const float invl = 1.0f / lrr;
            const int row = rbase + r;
            unsigned short* op = o + ((size_t)(b * SS + row) * QH + qh) * HD;
            #pragma unroll
            for (int t = 0; t < 8; ++t)
                op[t * 16 + l16] = f2bf(oacc[t][r] * invl);
        }
    }
}

// ---------------------------------------------------------------------------
extern "C" void kernel_launch(void* const* d_in, const int* in_sizes, int n_in,
                              void* d_out, int out_size, void* d_ws,
                              size_t ws_size, hipStream_t stream)
{
    const float* x         = (const float*)d_in[0];
    const int*   positions = (const int*)d_in[1];
    const float* Wq        = (const float*)d_in[2];
    const float* Wk        = (const float*)d_in[3];
    const float* Wv        = (const float*)d_in[4];
    const float* Wo        = (const float*)d_in[5];
    float* out = (float*)d_out;

    // workspace (60 MB):
    //   [ 0,16)  xb  bf16 [4096][2048]      -- aliased by opre after qkv gemm
    //   [16,28)  Wqkvt bf16 [3072][2048]    (B^T)
    //   [28,36)  Wot bf16 [2048][2048]      (B^T)
    //   [36,52)  qbf bf16 [4096][16][128]
    //   [52,56)  kbf bf16 [4096][4][128]
    //   [56,60)  vtb bf16 [2][4][128][2048] (V^T: [b][n][h][s])
    char* ws = (char*)d_ws;
    unsigned short* xb    = (unsigned short*)ws;
    unsigned short* Wqkvt = (unsigned short*)(ws + (16u << 20));
    unsigned short* Wot   = (unsigned short*)(ws + (28u << 20));
    unsigned short* qbf   = (unsigned short*)(ws + (36u << 20));
    unsigned short* kbf   = (unsigned short*)(ws + (52u << 20));
    unsigned short* vtb   = (unsigned short*)(ws + (56u << 20));
    unsigned short* opre  = xb;   // alias: xb dead after qkv gemm

    // fused prep: cast_x + Wq/Wk/Wv/Wo transpose-casts (1 launch)
    prep_kernel<<<14336, 256, 0, stream>>>(x, xb, Wq, Wk, Wv, Wo, Wqkvt, Wot);

    // qkv projection (v stored transposed)
    gemm_bt_kernel<<<dim3(32, 24), 256, 0, stream>>>(
        xb, Wqkvt, qbf, kbf, vtb, nullptr, 1);

    const int pairs = BB * SS * (QH + NKV) * 64;
    rope_kernel<<<(pairs + 255) / 256, 256, 0, stream>>>(qbf, kbf, positions);

    // attention: 512 blocks, paired tiles (66 rounds each), 3 blocks/CU
    dim3 g2(16, BB * QH);
    attn_kernel<<<g2, 256, 0, stream>>>(qbf, kbf, vtb, opre);

    // output projection
    gemm_bt_kernel<<<dim3(32, 16), 256, 0, stream>>>(
        opre, Wot, nullptr, nullptr, nullptr, out, 0);
}

// Round 12
// 304.045 us; speedup vs baseline: 1.1166x; 1.1166x over previous
//
#include <hip/hip_runtime.h>
#include <math.h>

#define BB 2
#define SS 2048
#define DD 2048
#define QH 16
#define NKV 4
#define HD 128
#define REP 4           // QH / NKV
#define NEG_INF_F (-1e9f)

typedef __bf16 bfrag __attribute__((ext_vector_type(8)));   // 4 VGPRs
typedef float  ffrag __attribute__((ext_vector_type(4)));   // 4 VGPRs

__device__ inline unsigned short f2bf(float f) {
    unsigned u = __builtin_bit_cast(unsigned, f);
    u += 0x7fff + ((u >> 16) & 1);          // round-to-nearest-even
    return (unsigned short)(u >> 16);
}
__device__ inline float bf2f(unsigned short u) {
    unsigned v = (unsigned)u << 16;
    return __builtin_bit_cast(float, v);
}
__device__ inline bfrag ld_frag(const unsigned short* p) {
    uint4 u = *(const uint4*)p;
    return __builtin_bit_cast(bfrag, u);
}
__device__ inline void async16(const void* g, void* l) {
    __builtin_amdgcn_global_load_lds(
        (const __attribute__((address_space(1))) unsigned int*)g,
        (__attribute__((address_space(3))) unsigned int*)l, 16, 0, 0);
}
// pack two floats to packed bf16
__device__ inline unsigned pkbf(float a, float b) {
    unsigned short ua = __builtin_bit_cast(unsigned short, (__bf16)a);
    unsigned short ub = __builtin_bit_cast(unsigned short, (__bf16)b);
    return (unsigned)ua | ((unsigned)ub << 16);
}

// ---------------------------------------------------------------------------
// Kernel P: fused prep — cast_x + all weight transpose-casts in ONE launch.
//   blocks [0,4096):        cast x fp32->bf16, 2048 elems/block
//   blocks [4096,10240):    tcast Wq/Wk/Wv (R=2048,C=128, 24 batches)
//   blocks [10240,14336):   tcast Wo (R=C=2048)
// ---------------------------------------------------------------------------
__global__ __launch_bounds__(256) void prep_kernel(
    const float* __restrict__ x, unsigned short* __restrict__ xb,
    const float* __restrict__ Wq, const float* __restrict__ Wk,
    const float* __restrict__ Wv, const float* __restrict__ Wo,
    unsigned short* __restrict__ Wqkvt, unsigned short* __restrict__ Wot)
{
    __shared__ float tile[32][33];
    const int blk = blockIdx.x;
    const int tid = threadIdx.x;

    if (blk < 4096) {
        const int i = blk * 2048 + tid * 8;
        float4 a = *(const float4*)(x + i);
        float4 b = *(const float4*)(x + i + 4);
        unsigned short o[8];
        o[0] = f2bf(a.x); o[1] = f2bf(a.y); o[2] = f2bf(a.z); o[3] = f2bf(a.w);
        o[4] = f2bf(b.x); o[5] = f2bf(b.y); o[6] = f2bf(b.z); o[7] = f2bf(b.w);
        *(uint4*)(xb + i) = *(uint4*)o;
        return;
    }

    const float* in;
    unsigned short* out;
    int R, C, bx, by;
    if (blk < 10240) {
        const int lw = blk - 4096;
        const int z  = lw >> 8;            // 0..23
        const int r  = lw & 255;
        bx = r & 3; by = r >> 2;
        R = 2048; C = 128;
        if (z < 16)      { in = Wq + (size_t)z * 2048 * 128;
                           out = Wqkvt + (size_t)z * 128 * 2048; }
        else if (z < 20) { in = Wk + (size_t)(z - 16) * 2048 * 128;
                           out = Wqkvt + (size_t)(16 + (z - 16)) * 128 * 2048; }
        else             { in = Wv + (size_t)(z - 20) * 2048 * 128;
                           out = Wqkvt + (size_t)(20 + (z - 20)) * 128 * 2048; }
    } else {
        const int lw = blk - 10240;
        bx = lw & 63; by = lw >> 6;
        R = 2048; C = 2048;
        in = Wo; out = Wot;
    }
    const int c0 = bx * 32, r0 = by * 32;
    const int tx = tid & 31, ty = tid >> 5;   // ty: 0..7
    #pragma unroll
    for (int k = 0; k < 4; ++k)
        tile[ty + 8 * k][tx] = in[(size_t)(r0 + ty + 8 * k) * C + c0 + tx];
    __syncthreads();
    #pragma unroll
    for (int k = 0; k < 4; ++k)
        out[(size_t)(c0 + ty + 8 * k) * R + r0 + tx] =
            f2bf(tile[tx][ty + 8 * k]);
}

// ---------------------------------------------------------------------------
// Kernel C: bf16 MFMA GEMM v7 — BK=64 + dbuf (round-9, 84.4 µs) with RoPE
// FUSED into the q/k epilogue (rope_kernel launch + 40 MB q/k round trip
// eliminated).
//  - Each mode-1 q/k block owns ONE head (128 cols) x 128 (b,s) rows. The
//    RoPE pair (h, h+64) spans waves 0<->1 / 2<->3, so the epilogue stages
//    the f32 acc tile in the dead staging LDS (ex[128][132] f32; stride 132
//    -> phase-1 writes 2-way (free), reads row-contiguous (free)), barriers
//    once, then each thread rotates one hh column over 32 rows (per-wave
//    uniform positions[s] broadcast; coalesced 64-lane stores).
//  - Rotation on f32 pre-rounding acc (>= previous accuracy); q scale
//    1/sqrt(128) folded into the rotation.
//  - Natural block order (XCD remaps measured worse, r4/r8); XOR-8 LDS
//    swizzle (0 conflicts, r7).
// mode 0: fp32 out [row][2048] (oproj).
// mode 1: q,k rotated bf16; v stored TRANSPOSED to vt[b][n][h][s].
// ---------------------------------------------------------------------------
__global__ __launch_bounds__(256) void gemm_bt_kernel(
    const unsigned short* __restrict__ A,
    const unsigned short* __restrict__ Bt,
    const int* __restrict__ positions,
    unsigned short* __restrict__ q_out, unsigned short* __restrict__ k_out,
    unsigned short* __restrict__ vt_out, float* __restrict__ f_out,
    int mode)
{
    const int m0 = blockIdx.x * 128;
    const int n0 = blockIdx.y * 128;
    const int tid  = threadIdx.x;
    const int w    = tid >> 6, lane = tid & 63;
    const int l16  = lane & 15, quad = lane >> 4;
    const int wm = (w >> 1) * 64, wn = (w & 1) * 64;
    const int sw8 = l16 & 7;                  // read-side swizzle key

    // 67,584 B: [0,32K) As dbuf, [32K,64K) Bs dbuf; epilogue reuses the
    // whole thing as ex[128][132] f32 exchange buffer.
    __shared__ __attribute__((aligned(16))) char smem[67584];
    unsigned short (*As)[128 * 64] = (unsigned short(*)[128 * 64])smem;
    unsigned short (*Bs)[128 * 64] =
        (unsigned short(*)[128 * 64])(smem + 32768);

    ffrag acc[4][4];
    #pragma unroll
    for (int mi = 0; mi < 4; ++mi)
        #pragma unroll
        for (int ni = 0; ni < 4; ++ni)
            acc[mi][ni] = (ffrag){0.f, 0.f, 0.f, 0.f};

    auto stage = [&](int d, int k0) {
        #pragma unroll
        for (int j = 0; j < 4; ++j) {
            const int i   = j * 256 + tid;        // granule 0..1023
            const int row = i >> 3;
            const int sl  = (i & 7) ^ (row & 7);
            async16(&A [(size_t)(m0 + row) * 2048 + k0 + sl * 8],
                    (char*)&As[d][0] + i * 16);
            async16(&Bt[(size_t)(n0 + row) * 2048 + k0 + sl * 8],
                    (char*)&Bs[d][0] + i * 16);
        }
    };

    stage(0, 0);
    __syncthreads();              // prologue drain: buffer 0 ready
    int cur = 0;
    for (int k0 = 0; k0 < 2048; k0 += 64) {
        if (k0 + 64 < 2048) stage(cur ^ 1, k0 + 64);

        #pragma unroll
        for (int c2 = 0; c2 < 2; ++c2) {
            bfrag af[4], bfr[4];
            #pragma unroll
            for (int mi = 0; mi < 4; ++mi)
                af[mi] = ld_frag(&As[cur][(wm + mi * 16 + l16) * 64
                                          + (((c2 * 4 + quad) ^ sw8) * 8)]);
            #pragma unroll
            for (int ni = 0; ni < 4; ++ni)
                bfr[ni] = ld_frag(&Bs[cur][(wn + ni * 16 + l16) * 64
                                           + (((c2 * 4 + quad) ^ sw8) * 8)]);
            #pragma unroll
            for (int mi = 0; mi < 4; ++mi)
                #pragma unroll
                for (int ni = 0; ni < 4; ++ni)
                    acc[mi][ni] = __builtin_amdgcn_mfma_f32_16x16x32_bf16(
                        af[mi], bfr[ni], acc[mi][ni], 0, 0, 0);
        }

        __syncthreads();
        cur ^= 1;
    }
    // after the final barrier all LDS reads are done -> smem reusable

    if (mode == 0) {
        #pragma unroll
        for (int mi = 0; mi < 4; ++mi)
            #pragma unroll
            for (int ni = 0; ni < 4; ++ni) {
                const int col = n0 + wn + ni * 16 + l16;
                #pragma unroll
                for (int r = 0; r < 4; ++r) {
                    const int row = m0 + wm + mi * 16 + quad * 4 + r;
                    f_out[(size_t)row * 2048 + col] = acc[mi][ni][r];
                }
            }
    } else if (n0 < 2560) {
        // ---- fused RoPE epilogue (one head per block) ----
        float* ex = (float*)smem;             // [128][132] f32
        #pragma unroll
        for (int mi = 0; mi < 4; ++mi)
            #pragma unroll
            for (int ni = 0; ni < 4; ++ni) {
                const int colL = wn + ni * 16 + l16;
                #pragma unroll
                for (int r = 0; r < 4; ++r) {
                    const int rowL = wm + mi * 16 + quad * 4 + r;
                    ex[rowL * 132 + colL] = acc[mi][ni][r];
                }
            }
        __syncthreads();

        const bool isq = (n0 < 2048);
        const int head = isq ? (n0 >> 7) : ((n0 - 2048) >> 7);
        const int hh = tid & 63;              // rotation pair (hh, hh+64)
        const int rg = tid >> 6;              // wave id: rows rg, rg+4, ...
        const float inv_ts = powf(10000.0f, -(float)hh * (1.0f / 64.0f));
        const float qsc = isq ? 0.08838834764831845f : 1.0f;
        for (int g = 0; g < 32; ++g) {
            const int rowL = g * 4 + rg;
            const int row  = m0 + rowL;
            const int b = row >> 11, s = row & 2047;
            const float pos = (float)positions[s];   // wave-uniform load
            const float angle = pos * inv_ts;
            const float sn = sinf(angle), cs = cosf(angle);
            const float x1 = ex[rowL * 132 + hh];
            const float x2 = ex[rowL * 132 + hh + 64];
            const unsigned short o1 = f2bf((x1 * cs - x2 * sn) * qsc);
            const unsigned short o2 = f2bf((x2 * cs + x1 * sn) * qsc);
            unsigned short* dst = isq
                ? q_out + ((size_t)(b * SS + s) * QH  + head) * HD
                : k_out + ((size_t)(b * SS + s) * NKV + head) * HD;
            dst[hh]      = o1;
            dst[hh + 64] = o2;
        }
    } else {
        // v region: transposed store vt[b][n][h][s], 4 bf16 (s..s+3) packed
        const int c3 = n0 - 2560;
        #pragma unroll
        for (int mi = 0; mi < 4; ++mi)
            #pragma unroll
            for (int ni = 0; ni < 4; ++ni) {
                const int col = c3 + wn + ni * 16 + l16;   // 0..511
                const int nh = col >> 7, h = col & 127;
                const int row0 = m0 + wm + mi * 16 + quad * 4;
                const int b = row0 >> 11, s = row0 & 2047;
                unsigned short pk[4];
                #pragma unroll
                for (int r = 0; r < 4; ++r) pk[r] = f2bf(acc[mi][ni][r]);
                *(uint2*)&vt_out[(((size_t)b * NKV + nh) * HD + h) * SS + s] =
                    *(uint2*)pk;
            }
    }
}

// ---------------------------------------------------------------------------
// Kernel E: causal flash attention v8 (rounds 4/7/9 measured-good version).
//  Paired tiles (33 rounds), double-buffered K/V via global_load_lds with
//  XOR-8 source-side swizzle, swapped QK^T + lane-local softmax, defer-max,
//  scale folded into q, setprio around MFMA clusters, XCD chunking.
// ---------------------------------------------------------------------------
__global__ __launch_bounds__(256, 2) void attn_kernel(
    const unsigned short* __restrict__ qb,
    const unsigned short* __restrict__ kb,
    const unsigned short* __restrict__ vt,
    unsigned short* __restrict__ o)
{
    // XCD-aware remap: flat = bh*16 + tile_x, chunks of 64 per XCD
    int f = blockIdx.y * 16 + blockIdx.x;
    f = (f & 7) * 64 + (f >> 3);                   // 512 blocks, bijective
    const int bh = f >> 4;
    const int bx = f & 15;

    const int b  = bh / QH, qh = bh % QH;
    const int n  = qh / REP;

    const int tid  = threadIdx.x;
    const int w    = tid >> 6;
    const int lane = tid & 63;
    const int l16  = lane & 15;
    const int quad = lane >> 4;
    const int sw   = l16 & 7;                      // read-side swizzle key

    __shared__ unsigned short Ks[2][2][64][64];    // 32 KB  [buf][cc][t][h64]
    __shared__ unsigned short Vs[2][128][64];      // 32 KB  [buf][h][t64]
    __shared__ unsigned short Ps[4][16][72];       // 9 KB   [wave][q][k64+pad]

    const unsigned short* kbase = kb + (size_t)b * (SS * NKV * HD) + n * HD;
    const unsigned short* vbase = vt + ((size_t)b * NKV + n) * HD * SS;

    for (int ph = 0; ph < 2; ++ph) {
        const int tile = ph == 0 ? (31 - bx) : bx;
        const int s0 = tile * 64;
        const int rbase = s0 + w * 16 + quad * 4;   // oacc row base
        const int thr   = w * 16 + l16;             // this lane's q (softmax)

        bfrag qf[4];
        {
            const unsigned short* qp =
                qb + ((size_t)(b * SS + s0 + w * 16 + l16) * QH + qh) * HD
                   + quad * 8;
            #pragma unroll
            for (int c = 0; c < 4; ++c) qf[c] = ld_frag(qp + c * 32);
        }
        ffrag oacc[8];
        #pragma unroll
        for (int t = 0; t < 8; ++t) oacc[t] = (ffrag){0.f, 0.f, 0.f, 0.f};
        float mr = -1e30f, lr = 0.0f;               // state for q-row l16

        // prologue: stage first K/V tile into buffer 0 (pre-swizzled source)
        #pragma unroll
        for (int j = 0; j < 4; ++j) {
            const int s = j * 256 + tid;
            {   const int cc = s >> 9, t = (s >> 3) & 63;
                const int sl = (s & 7) ^ (t & 7);
                async16(kbase + (size_t)t * (NKV * HD) + cc * 64 + sl * 8,
                        (char*)&Ks[0][0][0][0] + s * 16);
            }
            {   const int h = s >> 3, sl = (s & 7) ^ (h & 7);
                async16(vbase + (size_t)h * SS + sl * 8,
                        (char*)&Vs[0][0][0] + s * 16);
            }
        }
        __syncthreads();

        int p = 0;
        for (int t0 = 0; t0 <= s0; t0 += 64, p ^= 1) {
            // stage next tile into the other buffer (overlaps compute below)
            if (t0 + 64 <= s0) {
                const int tn = t0 + 64;
                #pragma unroll
                for (int j = 0; j < 4; ++j) {
                    const int s = j * 256 + tid;
                    {   const int cc = s >> 9, t = (s >> 3) & 63;
                        const int sl = (s & 7) ^ (t & 7);
                        async16(kbase + (size_t)(tn + t) * (NKV * HD)
                                      + cc * 64 + sl * 8,
                                (char*)&Ks[p ^ 1][0][0][0] + s * 16);
                    }
                    {   const int h = s >> 3, sl = (s & 7) ^ (h & 7);
                        async16(vbase + (size_t)h * SS + tn + sl * 8,
                                (char*)&Vs[p ^ 1][0][0] + s * 16);
                    }
                }
            }

            // --- QK^T on buffer p, SWAPPED operands: C[k-sub][q]
            ffrag sc[4];
            #pragma unroll
            for (int t = 0; t < 4; ++t) sc[t] = (ffrag){0.f, 0.f, 0.f, 0.f};
            __builtin_amdgcn_s_setprio(1);
            #pragma unroll
            for (int c = 0; c < 4; ++c) {
                const int cc = c >> 1, cb = (c & 1) * 4;
                #pragma unroll
                for (int t = 0; t < 4; ++t) {
                    bfrag kfr = ld_frag(
                        &Ks[p][cc][t * 16 + l16][((cb + quad) ^ sw) * 8]);
                    sc[t] = __builtin_amdgcn_mfma_f32_16x16x32_bf16(
                        kfr, qf[c], sc[t], 0, 0, 0);
                }
            }
            __builtin_amdgcn_s_setprio(0);

            // --- mask (lane holds q-row = l16; k = t0 + 16t + 4*quad + r)
            const bool diag = (t0 == s0);
            if (diag) {
                #pragma unroll
                for (int t = 0; t < 4; ++t) {
                    const int col0 = t * 16 + quad * 4;
                    #pragma unroll
                    for (int r = 0; r < 4; ++r)
                        if (col0 + r > thr) sc[t][r] = NEG_INF_F;
                }
            }

            // --- lane-local online softmax for q-row l16
            float tmax;
            {
                float a0 = fmaxf(fmaxf(sc[0][0], sc[0][1]),
                                 fmaxf(sc[0][2], sc[0][3]));
                float a1 = fmaxf(fmaxf(sc[1][0], sc[1][1]),
                                 fmaxf(sc[1][2], sc[1][3]));
                float a2 = fmaxf(fmaxf(sc[2][0], sc[2][1]),
                                 fmaxf(sc[2][2], sc[2][3]));
                float a3 = fmaxf(fmaxf(sc[3][0], sc[3][1]),
                                 fmaxf(sc[3][2], sc[3][3]));
                tmax = fmaxf(fmaxf(a0, a1), fmaxf(a2, a3));
            }
            tmax = fmaxf(tmax, __shfl_xor(tmax, 16));
            tmax = fmaxf(tmax, __shfl_xor(tmax, 32));

            if (__any(tmax > mr + 8.0f)) {
                const float mnew  = fmaxf(mr, tmax);
                const float alpha = __expf(mr - mnew);
                lr *= alpha;
                mr = mnew;
                // oacc rows are q = 4*quad+r: fetch that row's alpha
                #pragma unroll
                for (int r = 0; r < 4; ++r) {
                    const float ar =
                        __shfl(alpha, (lane & 48) | (quad * 4 + r));
                    #pragma unroll
                    for (int t = 0; t < 8; ++t) oacc[t][r] *= ar;
                }
            }

            float ps = 0.f;
            #pragma unroll
            for (int t = 0; t < 4; ++t) {
                const float p0 = __expf(sc[t][0] - mr);
                const float p1 = __expf(sc[t][1] - mr);
                const float p2 = __expf(sc[t][2] - mr);
                const float p3 = __expf(sc[t][3] - mr);
                ps += (p0 + p1) + (p2 + p3);
                uint2 pk2;
                pk2.x = pkbf(p0, p1);
                pk2.y = pkbf(p2, p3);
                *(uint2*)&Ps[w][l16][t * 16 + quad * 4] = pk2;
            }
            ps += __shfl_xor(ps, 16);
            ps += __shfl_xor(ps, 32);
            lr += ps;
            // wave-private Ps: same-wave LDS ordering, no barrier needed

            // --- PV on buffer p (swizzled V reads, conflict-free)
            __builtin_amdgcn_s_setprio(1);
            #pragma unroll
            for (int c = 0; c < 2; ++c) {
                bfrag pf = ld_frag(&Ps[w][l16][c * 32 + quad * 8]);
                #pragma unroll
                for (int t = 0; t < 8; ++t) {
                    bfrag vf = ld_frag(
                        &Vs[p][t * 16 + l16][((c * 4 + quad) ^ sw) * 8]);
                    oacc[t] = __builtin_amdgcn_mfma_f32_16x16x32_bf16(
                        pf, vf, oacc[t], 0, 0, 0);
                }
            }
            __builtin_amdgcn_s_setprio(0);

            // one barrier per round: drains next-tile staging (vmcnt0) after
            // compute, and orders this round's LDS reads vs next overwrite
            __syncthreads();
        }

        // --- epilogue (oacc rows are q = rbase + r; l at lane 4*quad+r)
        #pragma unroll
        for (int r = 0; r < 4; ++r) {
            const float lrr  = __shfl(lr, (lane & 48) | (quad * 4 + r));
            const float invl = 1.0f / lrr;
            const int row = rbase + r;
            unsigned short* op = o + ((size_t)(b * SS + row) * QH + qh) * HD;
            #pragma unroll
            for (int t = 0; t < 8; ++t)
                op[t * 16 + l16] = f2bf(oacc[t][r] * invl);
        }
    }
}

// ---------------------------------------------------------------------------
extern "C" void kernel_launch(void* const* d_in, const int* in_sizes, int n_in,
                              void* d_out, int out_size, void* d_ws,
                              size_t ws_size, hipStream_t stream)
{
    const float* x         = (const float*)d_in[0];
    const int*   positions = (const int*)d_in[1];
    const float* Wq        = (const float*)d_in[2];
    const float* Wk        = (const float*)d_in[3];
    const float* Wv        = (const float*)d_in[4];
    const float* Wo        = (const float*)d_in[5];
    float* out = (float*)d_out;

    // workspace (60 MB):
    //   [ 0,16)  xb  bf16 [4096][2048]      -- aliased by opre after qkv gemm
    //   [16,28)  Wqkvt bf16 [3072][2048]    (B^T)
    //   [28,36)  Wot bf16 [2048][2048]      (B^T)
    //   [36,52)  qbf bf16 [4096][16][128]
    //   [52,56)  kbf bf16 [4096][4][128]
    //   [56,60)  vtb bf16 [2][4][128][2048] (V^T: [b][n][h][s])
    char* ws = (char*)d_ws;
    unsigned short* xb    = (unsigned short*)ws;
    unsigned short* Wqkvt = (unsigned short*)(ws + (16u << 20));
    unsigned short* Wot   = (unsigned short*)(ws + (28u << 20));
    unsigned short* qbf   = (unsigned short*)(ws + (36u << 20));
    unsigned short* kbf   = (unsigned short*)(ws + (52u << 20));
    unsigned short* vtb   = (unsigned short*)(ws + (56u << 20));
    unsigned short* opre  = xb;   // alias: xb dead after qkv gemm

    // fused prep: cast_x + Wq/Wk/Wv/Wo transpose-casts (1 launch)
    prep_kernel<<<14336, 256, 0, stream>>>(x, xb, Wq, Wk, Wv, Wo, Wqkvt, Wot);

    // qkv projection with FUSED RoPE (v stored transposed)
    gemm_bt_kernel<<<dim3(32, 24), 256, 0, stream>>>(
        xb, Wqkvt, positions, qbf, kbf, vtb, nullptr, 1);

    // attention: 512 blocks, paired tiles (33 rounds each), 2 blocks/CU
    dim3 g2(16, BB * QH);
    attn_kernel<<<g2, 256, 0, stream>>>(qbf, kbf, vtb, opre);

    // output projection
    gemm_bt_kernel<<<dim3(32, 16), 256, 0, stream>>>(
        opre, Wot, positions, nullptr, nullptr, nullptr, out, 0);
}